// Round 5
// baseline (249.478 us; speedup 1.0000x reference)
//
#include <hip/hip_runtime.h>

// CP-decomposed 3D conv (AirConv3D): B=1, Cin=32, Cout=64, 56^3, K=3, pad=1, rank=53.
// ALL-F32 pipeline. Established by elimination across R1-R4:
//   - inputs are f32 (bf16 reads NaN'd with zero-OOB kernel; f32 reads finite)
//   - output is f32 (bf16 writes read back as packed-pair garbage -> absmax 3.19)
// ZERO d_ws use. d_out (f32, 64 slices x NP = 44.9 MB) doubles as scratch:
//   slices [53,64): T1 rank-chunk scratch (11 ranks/chunk, 5 chunks)
//   slices [0,53):  T2 per-rank separable conv output
// k3 projects [0,53) -> [0,64) + bias IN PLACE: thread p reads only column p,
// then writes only column p (no __restrict__ on T -> loads can't sink below
// may-alias stores; store set depends on all loads via acc anyway).

#define NP 175616   // 56*56*56
#define HSTR 3136   // 56*56
#define WSTR 56
#define CIN 32
#define RK 53
#define COUT 64
#define SCR 53      // first scratch slice in d_out

// ---- k1: T[SCR+lr, p] = sum_c x[c,p] * Ucin[c][r0+lr] ----
__global__ __launch_bounds__(256) void k1_chunk(
    const float* __restrict__ x, const float* __restrict__ Ucin,
    float* T, int r0, int nr)
{
    __shared__ float sU[11 * CIN];          // [lr][c]
    const int tid = threadIdx.x;
    for (int t = tid; t < nr * CIN; t += 256) {
        int lr = t >> 5, c = t & 31;        // t == lr*32 + c
        sU[t] = Ucin[c * RK + (r0 + lr)];
    }
    __syncthreads();

    const int p = blockIdx.x * 256 + tid;
    float xv[CIN];
#pragma unroll
    for (int c = 0; c < CIN; ++c) xv[c] = x[c * NP + p];
#pragma unroll 1
    for (int lr = 0; lr < nr; ++lr) {
        float acc = 0.f;
#pragma unroll
        for (int c = 0; c < CIN; ++c) acc += xv[c] * sU[lr * CIN + c];
        T[(size_t)(SCR + lr) * NP + p] = acc;
    }
}

// ---- k2: per-rank separable 3x3x3 conv, zero padding ----
// Tile 8x8 (h,w) x full 56 (d). Reads slice (SCR+lr), writes slice (r0+lr) — disjoint.
__global__ __launch_bounds__(256) void k2_chunk(
    const float* __restrict__ Ukh, const float* __restrict__ Ukw,
    const float* __restrict__ Ukd, float* T, int r0)
{
    __shared__ float sIn[5800];   // 10*10*58 padded input tile (23.2 KB)
    __shared__ float sA[5600];    // 10*10*56 after d-conv (22.4 KB)
    const int lr = blockIdx.z;
    const int r  = r0 + lr;
    const int h0 = blockIdx.x * 8, w0 = blockIdx.y * 8;
    const int tid = threadIdx.x;
    const float kh0 = Ukh[r], kh1 = Ukh[RK + r], kh2 = Ukh[2 * RK + r];
    const float kw0 = Ukw[r], kw1 = Ukw[RK + r], kw2 = Ukw[2 * RK + r];
    const float kd0 = Ukd[r], kd1 = Ukd[RK + r], kd2 = Ukd[2 * RK + r];
    const float* T1r = T + (size_t)(SCR + lr) * NP;

    for (int idx = tid; idx < 5800; idx += 256) {
        int d = idx % 58; int t2 = idx / 58; int ww = t2 % 10; int hh = t2 / 10;
        int gh = h0 + hh - 1, gw = w0 + ww - 1, gd = d - 1;
        float v = 0.f;
        if ((unsigned)gh < 56u && (unsigned)gw < 56u && (unsigned)gd < 56u)
            v = T1r[gh * HSTR + gw * WSTR + gd];
        sIn[idx] = v;
    }
    __syncthreads();

    // d-conv: sA[h'][w'][d] = sum_l sIn[h'][w'][d+l] * kd[l]
    for (int idx = tid; idx < 5600; idx += 256) {
        int d = idx % 56; int t2 = idx / 56; int ww = t2 % 10; int hh = t2 / 10;
        const float* b = &sIn[(hh * 10 + ww) * 58 + d];
        sA[idx] = b[0] * kd0 + b[1] * kd1 + b[2] * kd2;
    }
    __syncthreads();

    const float k00 = kh0 * kw0, k01 = kh0 * kw1, k02 = kh0 * kw2;
    const float k10 = kh1 * kw0, k11 = kh1 * kw1, k12 = kh1 * kw2;
    const float k20 = kh2 * kw0, k21 = kh2 * kw1, k22 = kh2 * kw2;

    // hw-conv: out[h][w][d] = sum_{i,j} sA[h+i][w+j][d] * kh[i]*kw[j]
    for (int idx = tid; idx < 3584; idx += 256) {
        int d = idx % 56; int t2 = idx / 56; int ww = t2 % 8; int hh = t2 / 8;
        const float* a = &sA[(hh * 10 + ww) * 56 + d];
        float acc = a[0]    * k00 + a[56]   * k01 + a[112]  * k02
                  + a[560]  * k10 + a[616]  * k11 + a[672]  * k12
                  + a[1120] * k20 + a[1176] * k21 + a[1232] * k22;
        T[(size_t)r * NP + (h0 + hh) * HSTR + (w0 + ww) * WSTR + d] = acc;
    }
}

// ---- k3: in-place projection, slices [0,53) -> [0,64) + bias ----
__global__ __launch_bounds__(256) void k3_out(
    float* T, const float* __restrict__ Ucout, const float* __restrict__ bias)
{
    __shared__ float sUo[RK * COUT];   // 13.6 KB
    __shared__ float sB[COUT];
    const int tid = threadIdx.x;
    for (int t = tid; t < RK * COUT; t += 256) sUo[t] = Ucout[t];
    if (tid < COUT) sB[tid] = bias[tid];
    __syncthreads();

    const int p = blockIdx.x * 256 + tid;
    float acc[COUT];
#pragma unroll
    for (int o = 0; o < COUT; ++o) acc[o] = sB[o];
#pragma unroll 1
    for (int r = 0; r < RK; ++r) {
        float t = T[(size_t)r * NP + p];
        const float* Ur = &sUo[r * COUT];
#pragma unroll
        for (int o = 0; o < COUT; ++o) acc[o] += t * Ur[o];
    }
#pragma unroll
    for (int o = 0; o < COUT; ++o) T[(size_t)o * NP + p] = acc[o];
}

extern "C" void kernel_launch(void* const* d_in, const int* in_sizes, int n_in,
                              void* d_out, int out_size, void* d_ws, size_t ws_size,
                              hipStream_t stream)
{
    const float* x     = (const float*)d_in[0];
    const float* Ukh   = (const float*)d_in[1];
    const float* Ukw   = (const float*)d_in[2];
    const float* Ukd   = (const float*)d_in[3];
    const float* Ucin  = (const float*)d_in[4];
    const float* Ucout = (const float*)d_in[5];
    const float* bias  = (const float*)d_in[6];
    float* T = (float*)d_out;   // 64 slices: [0,53)=T2, [53,64)=T1 scratch

    (void)d_ws; (void)ws_size;  // deliberately unused

    for (int r0 = 0; r0 < RK; r0 += 11) {
        int nr = (RK - r0 < 11) ? (RK - r0) : 11;
        k1_chunk<<<NP / 256, 256, 0, stream>>>(x, Ucin, T, r0, nr);
        k2_chunk<<<dim3(7, 7, nr), 256, 0, stream>>>(Ukh, Ukw, Ukd, T, r0);
    }
    k3_out<<<NP / 256, 256, 0, stream>>>(T, Ucout, bias);
}

// Round 6
// 185.388 us; speedup vs baseline: 1.3457x; 1.3457x over previous
//
#include <hip/hip_runtime.h>

// CP-decomposed 3D conv (AirConv3D): B=1, Cin=32, Cout=64, 56^3, K=3, pad=1, rank=53.
// All-f32 (established R1-R5). Fast path (ws_size >= 37.2MB):
//   k1_all: x (32,NP) x Ucin -> T1 (53,NP) in d_ws      [1 launch]
//   k2_all: per-rank separable 3x3x3 conv T1->T2, T2 in d_out slices [0,53)  [1 launch, z=53]
//   k3_out4: in-place projection 53->64 + bias, float4 + o-split-16 + unroll2
// Fallback (small ws): exact R5 pipeline (d_out doubles as scratch, 11 launches).

#define NP 175616   // 56*56*56
#define HSTR 3136   // 56*56
#define WSTR 56
#define CIN 32
#define RK 53
#define COUT 64
#define SCR 53      // first scratch slice in d_out (fallback path)

// ===================== fast path =====================

// T1[r,p] = sum_c x[c,p] * Ucin[c][r]
__global__ __launch_bounds__(256) void k1_all(
    const float* __restrict__ x, const float* __restrict__ Ucin,
    float* __restrict__ T1)
{
    __shared__ float sU[RK * CIN];          // [r][c], 6.8 KB
    const int tid = threadIdx.x;
    for (int t = tid; t < RK * CIN; t += 256) {
        int r = t >> 5, c = t & 31;
        sU[t] = Ucin[c * RK + r];
    }
    __syncthreads();

    const int p = blockIdx.x * 256 + tid;
    float xv[CIN];
#pragma unroll
    for (int c = 0; c < CIN; ++c) xv[c] = x[c * NP + p];
#pragma unroll 2
    for (int r = 0; r < RK; ++r) {
        float acc = 0.f;
#pragma unroll
        for (int c = 0; c < CIN; ++c) acc += xv[c] * sU[r * CIN + c];
        T1[(size_t)r * NP + p] = acc;
    }
}

// Per-rank separable 3x3x3 conv, zero padding. Tile 8x8 (h,w) x full 56 (d).
// Reads T1 slice r (ws), writes T2 slice r (d_out) — disjoint buffers.
__global__ __launch_bounds__(256) void k2_all(
    const float* __restrict__ T1, const float* __restrict__ Ukh,
    const float* __restrict__ Ukw, const float* __restrict__ Ukd,
    float* __restrict__ T2)
{
    __shared__ float sIn[5800];   // 10*10*58 padded input tile (23.2 KB)
    __shared__ float sA[5600];    // 10*10*56 after d-conv (22.4 KB)
    const int r  = blockIdx.z;
    const int h0 = blockIdx.x * 8, w0 = blockIdx.y * 8;
    const int tid = threadIdx.x;
    const float kh0 = Ukh[r], kh1 = Ukh[RK + r], kh2 = Ukh[2 * RK + r];
    const float kw0 = Ukw[r], kw1 = Ukw[RK + r], kw2 = Ukw[2 * RK + r];
    const float kd0 = Ukd[r], kd1 = Ukd[RK + r], kd2 = Ukd[2 * RK + r];
    const float* T1r = T1 + (size_t)r * NP;

    for (int idx = tid; idx < 5800; idx += 256) {
        int d = idx % 58; int t2 = idx / 58; int ww = t2 % 10; int hh = t2 / 10;
        int gh = h0 + hh - 1, gw = w0 + ww - 1, gd = d - 1;
        float v = 0.f;
        if ((unsigned)gh < 56u && (unsigned)gw < 56u && (unsigned)gd < 56u)
            v = T1r[gh * HSTR + gw * WSTR + gd];
        sIn[idx] = v;
    }
    __syncthreads();

    for (int idx = tid; idx < 5600; idx += 256) {
        int d = idx % 56; int t2 = idx / 56; int ww = t2 % 10; int hh = t2 / 10;
        const float* b = &sIn[(hh * 10 + ww) * 58 + d];
        sA[idx] = b[0] * kd0 + b[1] * kd1 + b[2] * kd2;
    }
    __syncthreads();

    const float k00 = kh0 * kw0, k01 = kh0 * kw1, k02 = kh0 * kw2;
    const float k10 = kh1 * kw0, k11 = kh1 * kw1, k12 = kh1 * kw2;
    const float k20 = kh2 * kw0, k21 = kh2 * kw1, k22 = kh2 * kw2;

    for (int idx = tid; idx < 3584; idx += 256) {
        int d = idx % 56; int t2 = idx / 56; int ww = t2 % 8; int hh = t2 / 8;
        const float* a = &sA[(hh * 10 + ww) * 56 + d];
        float acc = a[0]    * k00 + a[56]   * k01 + a[112]  * k02
                  + a[560]  * k10 + a[616]  * k11 + a[672]  * k12
                  + a[1120] * k20 + a[1176] * k21 + a[1232] * k22;
        T2[(size_t)r * NP + (h0 + hh) * HSTR + (w0 + ww) * WSTR + d] = acc;
    }
}

// In-place projection with float4 + o-split. Thread = (quad q, o-group og).
// All 4 og-lanes of a quad are lanes of ONE wave (tid = 4*q_local + og_idx),
// so every lane's 53 reads (program order) precede any lane's stores — safe.
__global__ __launch_bounds__(256) void k3_out4(
    float* T, const float* __restrict__ Ucout, const float* __restrict__ bias)
{
    __shared__ float sUo[RK * COUT + COUT];   // 13.8 KB
    const int tid = threadIdx.x;
    for (int t = tid; t < RK * COUT; t += 256) sUo[t] = Ucout[t];
    if (tid < COUT) sUo[RK * COUT + tid] = bias[tid];
    __syncthreads();

    const int q  = blockIdx.x * 64 + (tid >> 2);   // float4 column index
    const int og = (tid & 3) * 16;                 // 16 out-channels per lane
    const float4* Tv = (const float4*)T;           // slice stride NP/4 quads

    float4 a[16];
#pragma unroll
    for (int o = 0; o < 16; ++o) {
        float b = sUo[RK * COUT + og + o];
        a[o] = make_float4(b, b, b, b);
    }
#pragma unroll 2
    for (int r = 0; r < RK; ++r) {
        float4 t = Tv[(size_t)r * (NP / 4) + q];
        const float* Ur = &sUo[r * COUT + og];
#pragma unroll
        for (int o = 0; o < 16; ++o) {
            float u = Ur[o];
            a[o].x += t.x * u; a[o].y += t.y * u;
            a[o].z += t.z * u; a[o].w += t.w * u;
        }
    }
    float4* Ov = (float4*)T;
#pragma unroll
    for (int o = 0; o < 16; ++o)
        Ov[(size_t)(og + o) * (NP / 4) + q] = a[o];
}

// ===================== fallback path (R5, known good) =====================

__global__ __launch_bounds__(256) void k1_chunk(
    const float* __restrict__ x, const float* __restrict__ Ucin,
    float* T, int r0, int nr)
{
    __shared__ float sU[11 * CIN];
    const int tid = threadIdx.x;
    for (int t = tid; t < nr * CIN; t += 256) {
        int lr = t >> 5, c = t & 31;
        sU[t] = Ucin[c * RK + (r0 + lr)];
    }
    __syncthreads();

    const int p = blockIdx.x * 256 + tid;
    float xv[CIN];
#pragma unroll
    for (int c = 0; c < CIN; ++c) xv[c] = x[c * NP + p];
#pragma unroll 1
    for (int lr = 0; lr < nr; ++lr) {
        float acc = 0.f;
#pragma unroll
        for (int c = 0; c < CIN; ++c) acc += xv[c] * sU[lr * CIN + c];
        T[(size_t)(SCR + lr) * NP + p] = acc;
    }
}

__global__ __launch_bounds__(256) void k2_chunk(
    const float* __restrict__ Ukh, const float* __restrict__ Ukw,
    const float* __restrict__ Ukd, float* T, int r0)
{
    __shared__ float sIn[5800];
    __shared__ float sA[5600];
    const int lr = blockIdx.z;
    const int r  = r0 + lr;
    const int h0 = blockIdx.x * 8, w0 = blockIdx.y * 8;
    const int tid = threadIdx.x;
    const float kh0 = Ukh[r], kh1 = Ukh[RK + r], kh2 = Ukh[2 * RK + r];
    const float kw0 = Ukw[r], kw1 = Ukw[RK + r], kw2 = Ukw[2 * RK + r];
    const float kd0 = Ukd[r], kd1 = Ukd[RK + r], kd2 = Ukd[2 * RK + r];
    const float* T1r = T + (size_t)(SCR + lr) * NP;

    for (int idx = tid; idx < 5800; idx += 256) {
        int d = idx % 58; int t2 = idx / 58; int ww = t2 % 10; int hh = t2 / 10;
        int gh = h0 + hh - 1, gw = w0 + ww - 1, gd = d - 1;
        float v = 0.f;
        if ((unsigned)gh < 56u && (unsigned)gw < 56u && (unsigned)gd < 56u)
            v = T1r[gh * HSTR + gw * WSTR + gd];
        sIn[idx] = v;
    }
    __syncthreads();

    for (int idx = tid; idx < 5600; idx += 256) {
        int d = idx % 56; int t2 = idx / 56; int ww = t2 % 10; int hh = t2 / 10;
        const float* b = &sIn[(hh * 10 + ww) * 58 + d];
        sA[idx] = b[0] * kd0 + b[1] * kd1 + b[2] * kd2;
    }
    __syncthreads();

    const float k00 = kh0 * kw0, k01 = kh0 * kw1, k02 = kh0 * kw2;
    const float k10 = kh1 * kw0, k11 = kh1 * kw1, k12 = kh1 * kw2;
    const float k20 = kh2 * kw0, k21 = kh2 * kw1, k22 = kh2 * kw2;

    for (int idx = tid; idx < 3584; idx += 256) {
        int d = idx % 56; int t2 = idx / 56; int ww = t2 % 8; int hh = t2 / 8;
        const float* a = &sA[(hh * 10 + ww) * 56 + d];
        float acc = a[0]    * k00 + a[56]   * k01 + a[112]  * k02
                  + a[560]  * k10 + a[616]  * k11 + a[672]  * k12
                  + a[1120] * k20 + a[1176] * k21 + a[1232] * k22;
        T[(size_t)r * NP + (h0 + hh) * HSTR + (w0 + ww) * WSTR + d] = acc;
    }
}

__global__ __launch_bounds__(256) void k3_out(
    float* T, const float* __restrict__ Ucout, const float* __restrict__ bias)
{
    __shared__ float sUo[RK * COUT];
    __shared__ float sB[COUT];
    const int tid = threadIdx.x;
    for (int t = tid; t < RK * COUT; t += 256) sUo[t] = Ucout[t];
    if (tid < COUT) sB[tid] = bias[tid];
    __syncthreads();

    const int p = blockIdx.x * 256 + tid;
    float acc[COUT];
#pragma unroll
    for (int o = 0; o < COUT; ++o) acc[o] = sB[o];
#pragma unroll 1
    for (int r = 0; r < RK; ++r) {
        float t = T[(size_t)r * NP + p];
        const float* Ur = &sUo[r * COUT];
#pragma unroll
        for (int o = 0; o < COUT; ++o) acc[o] += t * Ur[o];
    }
#pragma unroll
    for (int o = 0; o < COUT; ++o) T[(size_t)o * NP + p] = acc[o];
}

// ===================== launch =====================

extern "C" void kernel_launch(void* const* d_in, const int* in_sizes, int n_in,
                              void* d_out, int out_size, void* d_ws, size_t ws_size,
                              hipStream_t stream)
{
    const float* x     = (const float*)d_in[0];
    const float* Ukh   = (const float*)d_in[1];
    const float* Ukw   = (const float*)d_in[2];
    const float* Ukd   = (const float*)d_in[3];
    const float* Ucin  = (const float*)d_in[4];
    const float* Ucout = (const float*)d_in[5];
    const float* bias  = (const float*)d_in[6];
    float* T = (float*)d_out;

    const size_t t1_bytes = (size_t)RK * NP * sizeof(float);   // 37.2 MB

    if (ws_size >= t1_bytes) {
        float* T1 = (float*)d_ws;
        k1_all<<<NP / 256, 256, 0, stream>>>(x, Ucin, T1);
        k2_all<<<dim3(7, 7, RK), 256, 0, stream>>>(T1, Ukh, Ukw, Ukd, T);
        k3_out4<<<NP / 256, 256, 0, stream>>>(T, Ucout, bias);
    } else {
        for (int r0 = 0; r0 < RK; r0 += 11) {
            int nr = (RK - r0 < 11) ? (RK - r0) : 11;
            k1_chunk<<<NP / 256, 256, 0, stream>>>(x, Ucin, T, r0, nr);
            k2_chunk<<<dim3(7, 7, nr), 256, 0, stream>>>(Ukh, Ukw, Ukd, T, r0);
        }
        k3_out<<<NP / 256, 256, 0, stream>>>(T, Ucout, bias);
    }
}

// Round 7
// 174.134 us; speedup vs baseline: 1.4327x; 1.0646x over previous
//
#include <hip/hip_runtime.h>

// CP-decomposed 3D conv (AirConv3D): B=1, Cin=32, Cout=64, 56^3, K=3, pad=1, rank=53.
// All-f32 (established R1-R5). ws_size >= 37.2MB established R6 (fast path ran).
// R7 structure:
//   k0_t : transpose Ucin -> Ut[r][c] in d_out[0:1696] (scratch; k3b overwrites later)
//   k1f4 : x (float4 cols) x Ut -> T1 (53,NP) in ws. Weights via uniform s_load (no LDS).
//   k2a  : per-(r,h)-plane d-conv + w-conv, IN PLACE on T1 (reads own plane into LDS,
//          barriers, writes same plane back; blocks fully disjoint). h-conv deferred.
//   k3b  : fused h-conv + 53->64 projection + bias. Per-wave o-group (og uniform via
//          readfirstlane -> weights s_load). Reads ws, writes d_out. No LDS.
// Fallback (small ws): R5 pipeline (known good).

#define NP 175616   // 56*56*56
#define NQ 43904    // NP/4 float4 columns
#define HSTR 3136   // 56*56
#define CIN 32
#define RK 53
#define COUT 64
#define SCR 53      // fallback scratch slice base in d_out

// ---- k0: Ut[r*32+c] = Ucin[c*53+r]  (1696 floats into d_out scratch) ----
__global__ __launch_bounds__(256) void k0_t(const float* __restrict__ Ucin,
                                            float* __restrict__ Ut)
{
    int t = blockIdx.x * 256 + threadIdx.x;
    if (t < RK * CIN) {
        int r = t >> 5, c = t & 31;
        Ut[t] = Ucin[c * RK + r];
    }
}

// ---- k1: T1[r,q] = sum_c x4[c,q] * Ut[r][c] ----
__global__ __launch_bounds__(256) void k1f4(
    const float4* __restrict__ x4, const float* __restrict__ Ut,
    float4* __restrict__ T1)
{
    const int q = blockIdx.x * 256 + threadIdx.x;
    if (q >= NQ) return;
    float4 xv[CIN];
#pragma unroll
    for (int c = 0; c < CIN; ++c) xv[c] = x4[(size_t)c * NQ + q];
#pragma unroll 2
    for (int r = 0; r < RK; ++r) {
        const float* U = Ut + r * CIN;    // uniform -> s_load_dwordx16 x2
        float4 a; a.x = 0.f; a.y = 0.f; a.z = 0.f; a.w = 0.f;
#pragma unroll
        for (int c = 0; c < CIN; ++c) {
            float u = U[c];
            a.x += xv[c].x * u; a.y += xv[c].y * u;
            a.z += xv[c].z * u; a.w += xv[c].w * u;
        }
        T1[(size_t)r * NQ + q] = a;
    }
}

// ---- k2a: in-plane d-conv + w-conv, in place on T1. grid (56 h, 53 r) ----
__global__ __launch_bounds__(256) void k2a(
    float* T1, const float* __restrict__ Ukw, const float* __restrict__ Ukd)
{
    __shared__ float sIn[56 * 58];   // [w][d+1], zero d-halo at 0,57  (13 KB)
    __shared__ float sA [58 * 56];   // [w+1][d], zero w-halo rows 0,57 (13 KB)
    const int h = blockIdx.x;
    const int r = blockIdx.y;
    const int tid = threadIdx.x;
    const float kd0 = Ukd[r], kd1 = Ukd[RK + r], kd2 = Ukd[2 * RK + r];
    const float kw0 = Ukw[r], kw1 = Ukw[RK + r], kw2 = Ukw[2 * RK + r];
    float* P = T1 + (size_t)r * NP + h * HSTR;   // this block's 3136-float plane

    for (int t = tid; t < 112; t += 256) {       // halos
        int i = t >> 1;
        if (t & 1) { sIn[i * 58] = 0.f; sIn[i * 58 + 57] = 0.f; }
        else       { sA[i] = 0.f;       sA[57 * 56 + i] = 0.f; }
    }
    for (int idx = tid; idx < 3136; idx += 256) {   // contiguous plane load
        int w = idx / 56, d = idx - w * 56;
        sIn[w * 58 + d + 1] = P[idx];
    }
    __syncthreads();
    for (int idx = tid; idx < 3136; idx += 256) {   // d-conv
        int w = idx / 56, d = idx - w * 56;
        const float* b = &sIn[w * 58 + d];
        sA[(w + 1) * 56 + d] = b[0] * kd0 + b[1] * kd1 + b[2] * kd2;
    }
    __syncthreads();
    for (int idx = tid; idx < 3136; idx += 256) {   // w-conv, write back in place
        const float* a = &sA[idx];                  // sA[w][d] = logical (w-1)
        P[idx] = a[0] * kw0 + a[56] * kw1 + a[112] * kw2;
    }
}

// ---- k3b: out[o,p] = sum_r kh-blend(Ta[r,h-1..h+1,p']) * Ucout[r][o] + bias[o] ----
// Wave w of the block owns o-group og = w*16 (uniform). 64 quads per block.
__global__ __launch_bounds__(256) void k3b(
    const float4* __restrict__ Ta, const float* __restrict__ Ucout,
    const float* __restrict__ bias, const float* __restrict__ Ukh,
    float4* __restrict__ Out)
{
    const int lane = threadIdx.x & 63;
    int og = (threadIdx.x >> 6) << 4;
    og = __builtin_amdgcn_readfirstlane(og);       // force SGPR -> s_load weights
    const int q = blockIdx.x * 64 + lane;          // float4 column, exact cover
    const int h = q / 784;                          // 784 quads per h-plane
    const bool hm = (h > 0), hp = (h < 55);

    float4 a[16];
#pragma unroll
    for (int o = 0; o < 16; ++o) {
        float b = bias[og + o];
        a[o].x = b; a[o].y = b; a[o].z = b; a[o].w = b;
    }
#pragma unroll 2
    for (int r = 0; r < RK; ++r) {
        const float4* S = Ta + (size_t)r * NQ + q;
        const float k0 = Ukh[r], k1 = Ukh[RK + r], k2 = Ukh[2 * RK + r];
        float4 B = S[0];
        float4 A; A.x = 0.f; A.y = 0.f; A.z = 0.f; A.w = 0.f;
        float4 C = A;
        if (hm) A = S[-784];
        if (hp) C = S[784];
        float4 t;
        t.x = A.x * k0 + B.x * k1 + C.x * k2;
        t.y = A.y * k0 + B.y * k1 + C.y * k2;
        t.z = A.z * k0 + B.z * k1 + C.z * k2;
        t.w = A.w * k0 + B.w * k1 + C.w * k2;
        const float* Ur = Ucout + r * COUT + og;   // uniform -> s_load_dwordx16
#pragma unroll
        for (int o = 0; o < 16; ++o) {
            float u = Ur[o];
            a[o].x += t.x * u; a[o].y += t.y * u;
            a[o].z += t.z * u; a[o].w += t.w * u;
        }
    }
#pragma unroll
    for (int o = 0; o < 16; ++o)
        Out[(size_t)(og + o) * NQ + q] = a[o];
}

// ===================== fallback path (R5, known good) =====================

__global__ __launch_bounds__(256) void k1_chunk(
    const float* __restrict__ x, const float* __restrict__ Ucin,
    float* T, int r0, int nr)
{
    __shared__ float sU[11 * CIN];
    const int tid = threadIdx.x;
    for (int t = tid; t < nr * CIN; t += 256) {
        int lr = t >> 5, c = t & 31;
        sU[t] = Ucin[c * RK + (r0 + lr)];
    }
    __syncthreads();
    const int p = blockIdx.x * 256 + tid;
    float xv[CIN];
#pragma unroll
    for (int c = 0; c < CIN; ++c) xv[c] = x[c * NP + p];
#pragma unroll 1
    for (int lr = 0; lr < nr; ++lr) {
        float acc = 0.f;
#pragma unroll
        for (int c = 0; c < CIN; ++c) acc += xv[c] * sU[lr * CIN + c];
        T[(size_t)(SCR + lr) * NP + p] = acc;
    }
}

__global__ __launch_bounds__(256) void k2_chunk(
    const float* __restrict__ Ukh, const float* __restrict__ Ukw,
    const float* __restrict__ Ukd, float* T, int r0)
{
    __shared__ float sIn[5800];
    __shared__ float sA[5600];
    const int lr = blockIdx.z;
    const int r  = r0 + lr;
    const int h0 = blockIdx.x * 8, w0 = blockIdx.y * 8;
    const int tid = threadIdx.x;
    const float kh0 = Ukh[r], kh1 = Ukh[RK + r], kh2 = Ukh[2 * RK + r];
    const float kw0 = Ukw[r], kw1 = Ukw[RK + r], kw2 = Ukw[2 * RK + r];
    const float kd0 = Ukd[r], kd1 = Ukd[RK + r], kd2 = Ukd[2 * RK + r];
    const float* T1r = T + (size_t)(SCR + lr) * NP;

    for (int idx = tid; idx < 5800; idx += 256) {
        int d = idx % 58; int t2 = idx / 58; int ww = t2 % 10; int hh = t2 / 10;
        int gh = h0 + hh - 1, gw = w0 + ww - 1, gd = d - 1;
        float v = 0.f;
        if ((unsigned)gh < 56u && (unsigned)gw < 56u && (unsigned)gd < 56u)
            v = T1r[gh * HSTR + gw * 56 + gd];
        sIn[idx] = v;
    }
    __syncthreads();
    for (int idx = tid; idx < 5600; idx += 256) {
        int d = idx % 56; int t2 = idx / 56; int ww = t2 % 10; int hh = t2 / 10;
        const float* b = &sIn[(hh * 10 + ww) * 58 + d];
        sA[idx] = b[0] * kd0 + b[1] * kd1 + b[2] * kd2;
    }
    __syncthreads();
    const float k00 = kh0 * kw0, k01 = kh0 * kw1, k02 = kh0 * kw2;
    const float k10 = kh1 * kw0, k11 = kh1 * kw1, k12 = kh1 * kw2;
    const float k20 = kh2 * kw0, k21 = kh2 * kw1, k22 = kh2 * kw2;
    for (int idx = tid; idx < 3584; idx += 256) {
        int d = idx % 56; int t2 = idx / 56; int ww = t2 % 8; int hh = t2 / 8;
        const float* a = &sA[(hh * 10 + ww) * 56 + d];
        float acc = a[0]    * k00 + a[56]   * k01 + a[112]  * k02
                  + a[560]  * k10 + a[616]  * k11 + a[672]  * k12
                  + a[1120] * k20 + a[1176] * k21 + a[1232] * k22;
        T[(size_t)r * NP + (h0 + hh) * HSTR + (w0 + ww) * 56 + d] = acc;
    }
}

__global__ __launch_bounds__(256) void k3_out(
    float* T, const float* __restrict__ Ucout, const float* __restrict__ bias)
{
    __shared__ float sUo[RK * COUT];
    __shared__ float sB[COUT];
    const int tid = threadIdx.x;
    for (int t = tid; t < RK * COUT; t += 256) sUo[t] = Ucout[t];
    if (tid < COUT) sB[tid] = bias[tid];
    __syncthreads();
    const int p = blockIdx.x * 256 + tid;
    float acc[COUT];
#pragma unroll
    for (int o = 0; o < COUT; ++o) acc[o] = sB[o];
#pragma unroll 1
    for (int r = 0; r < RK; ++r) {
        float t = T[(size_t)r * NP + p];
        const float* Ur = &sUo[r * COUT];
#pragma unroll
        for (int o = 0; o < COUT; ++o) acc[o] += t * Ur[o];
    }
#pragma unroll
    for (int o = 0; o < COUT; ++o) T[(size_t)o * NP + p] = acc[o];
}

// ===================== launch =====================

extern "C" void kernel_launch(void* const* d_in, const int* in_sizes, int n_in,
                              void* d_out, int out_size, void* d_ws, size_t ws_size,
                              hipStream_t stream)
{
    const float* x     = (const float*)d_in[0];
    const float* Ukh   = (const float*)d_in[1];
    const float* Ukw   = (const float*)d_in[2];
    const float* Ukd   = (const float*)d_in[3];
    const float* Ucin  = (const float*)d_in[4];
    const float* Ucout = (const float*)d_in[5];
    const float* bias  = (const float*)d_in[6];

    const size_t t1_bytes = (size_t)RK * NP * sizeof(float);   // 37.2 MB

    if (ws_size >= t1_bytes) {
        float* T1 = (float*)d_ws;
        float* Ut = (float*)d_out;    // 6.8 KB scratch, overwritten by k3b
        k0_t<<<7, 256, 0, stream>>>(Ucin, Ut);
        k1f4<<<(NQ + 255) / 256, 256, 0, stream>>>((const float4*)x, Ut, (float4*)T1);
        k2a<<<dim3(56, RK), 256, 0, stream>>>(T1, Ukw, Ukd);
        k3b<<<NQ / 64, 256, 0, stream>>>((const float4*)T1, Ucout, bias, Ukh,
                                         (float4*)d_out);
    } else {
        float* T = (float*)d_out;
        for (int r0 = 0; r0 < RK; r0 += 11) {
            int nr = (RK - r0 < 11) ? (RK - r0) : 11;
            k1_chunk<<<NP / 256, 256, 0, stream>>>(x, Ucin, T, r0, nr);
            k2_chunk<<<dim3(7, 7, nr), 256, 0, stream>>>(Ukh, Ukw, Ukd, T, r0);
        }
        k3_out<<<NP / 256, 256, 0, stream>>>(T, Ucout, bias);
    }
}

// Round 8
// 173.205 us; speedup vs baseline: 1.4404x; 1.0054x over previous
//
#include <hip/hip_runtime.h>

// CP-decomposed 3D conv (AirConv3D): B=1, Cin=32, Cout=64, 56^3, K=3, pad=1, rank=53.
// All-f32 (R1-R5). ws ~268 MB (R6/R7: fills of 262144 KB on d_ws).
// R8:
//   k0_t : transpose Ucin -> Ut[r][c], stored in ws AFTER T1 (no d_out aliasing)
//   k1n  : scalar-p pointwise 32->53, weights via uniform s_load, no LDS. 686 blocks.
//   k2n  : per-(r,h)-plane d-conv + w-conv in place on T1, float4 global+LDS ops.
//   k3n  : fused h-conv + 53->64 projection + bias, per-wave o-group (s_load weights).
// Fallback (small ws): R5 pipeline (known good).

#define NP 175616   // 56*56*56
#define NQ 43904    // NP/4 float4 columns
#define HSTR 3136   // 56*56
#define QH 784      // HSTR/4 quads per h-plane
#define CIN 32
#define RK 53
#define COUT 64
#define SCR 53      // fallback scratch slice base in d_out

// ---- k0: Ut[r*32+c] = Ucin[c*53+r] ----
__global__ __launch_bounds__(256) void k0_t(const float* __restrict__ Ucin,
                                            float* __restrict__ Ut)
{
    int t = blockIdx.x * 256 + threadIdx.x;
    if (t < RK * CIN) {
        int r = t >> 5, c = t & 31;
        Ut[t] = Ucin[c * RK + r];
    }
}

// ---- k1n: T1[r,p] = sum_c x[c,p] * Ut[r][c]  (686 blocks, no LDS) ----
__global__ __launch_bounds__(256) void k1n(
    const float* __restrict__ x, const float* __restrict__ Ut,
    float* __restrict__ T1)
{
    const int p = blockIdx.x * 256 + threadIdx.x;
    float xv[CIN];
#pragma unroll
    for (int c = 0; c < CIN; ++c) xv[c] = x[c * NP + p];
#pragma unroll 2
    for (int r = 0; r < RK; ++r) {
        const float* U = Ut + r * CIN;      // uniform -> s_load
        float acc = 0.f;
#pragma unroll
        for (int c = 0; c < CIN; ++c) acc += xv[c] * U[c];
        T1[(size_t)r * NP + p] = acc;
    }
}

// ---- k2n: in-plane d-conv + w-conv, in place on T1. grid (56 h, 53 r) ----
// Plane = 3136 floats = 784 float4. LDS unpadded [56][56] (float4-aligned).
__global__ __launch_bounds__(256) void k2n(
    float* T1, const float* __restrict__ Ukw, const float* __restrict__ Ukd)
{
    __shared__ float sIn[3136];
    __shared__ float sA[3136];
    const int h = blockIdx.x;
    const int r = blockIdx.y;
    const int tid = threadIdx.x;
    const float kd0 = Ukd[r], kd1 = Ukd[RK + r], kd2 = Ukd[2 * RK + r];
    const float kw0 = Ukw[r], kw1 = Ukw[RK + r], kw2 = Ukw[2 * RK + r];
    float4* P4 = (float4*)(T1 + (size_t)r * NP + h * HSTR);

    for (int i = tid; i < QH; i += 256)
        ((float4*)sIn)[i] = P4[i];
    __syncthreads();

    for (int i = tid; i < QH; i += 256) {        // d-conv
        int w = i / 14, d0 = (i - w * 14) * 4;
        const float* b = &sIn[w * 56 + d0];
        float4 c = *(const float4*)b;
        float lm = (d0 > 0)  ? b[-1] : 0.f;
        float rp = (d0 < 52) ? b[4]  : 0.f;
        float4 o;
        o.x = lm  * kd0 + c.x * kd1 + c.y * kd2;
        o.y = c.x * kd0 + c.y * kd1 + c.z * kd2;
        o.z = c.y * kd0 + c.z * kd1 + c.w * kd2;
        o.w = c.z * kd0 + c.w * kd1 + rp  * kd2;
        ((float4*)sA)[i] = o;
    }
    __syncthreads();

    for (int i = tid; i < QH; i += 256) {        // w-conv, write back in place
        int w = i / 14;
        float4 m = ((const float4*)sA)[i];
        float4 a0, a2;
        a0.x = a0.y = a0.z = a0.w = 0.f; a2 = a0;
        if (w > 0)  a0 = ((const float4*)sA)[i - 14];
        if (w < 55) a2 = ((const float4*)sA)[i + 14];
        float4 res;
        res.x = a0.x * kw0 + m.x * kw1 + a2.x * kw2;
        res.y = a0.y * kw0 + m.y * kw1 + a2.y * kw2;
        res.z = a0.z * kw0 + m.z * kw1 + a2.z * kw2;
        res.w = a0.w * kw0 + m.w * kw1 + a2.w * kw2;
        P4[i] = res;
    }
}

// ---- k3n: out[o,q] = sum_r kh-blend(Ta[r, h-1..h+1, q]) * Ucout[r][o] + bias[o] ----
// Block = 64 q x 4 og-waves; og uniform via readfirstlane -> weights s_load.
__global__ __launch_bounds__(256, 4) void k3n(
    const float4* __restrict__ Ta, const float* __restrict__ Ucout,
    const float* __restrict__ bias, const float* __restrict__ Ukh,
    float4* __restrict__ Out)
{
    const int lane = threadIdx.x & 63;
    int og = (threadIdx.x >> 6) << 4;
    og = __builtin_amdgcn_readfirstlane(og);
    const int q = blockIdx.x * 64 + lane;
    const int h = q / QH;
    const bool hm = (h > 0), hp = (h < 55);

    float4 a[16];
#pragma unroll
    for (int o = 0; o < 16; ++o) {
        float b = bias[og + o];
        a[o].x = b; a[o].y = b; a[o].z = b; a[o].w = b;
    }
#pragma unroll 2
    for (int r = 0; r < RK; ++r) {
        const float4* S = Ta + (size_t)r * NQ + q;
        const float k0 = Ukh[r], k1 = Ukh[RK + r], k2 = Ukh[2 * RK + r];
        float4 B = S[0];
        float4 A; A.x = 0.f; A.y = 0.f; A.z = 0.f; A.w = 0.f;
        float4 C = A;
        if (hm) A = S[-QH];
        if (hp) C = S[QH];
        float4 t;
        t.x = A.x * k0 + B.x * k1 + C.x * k2;
        t.y = A.y * k0 + B.y * k1 + C.y * k2;
        t.z = A.z * k0 + B.z * k1 + C.z * k2;
        t.w = A.w * k0 + B.w * k1 + C.w * k2;
        const float* Ur = Ucout + r * COUT + og;   // uniform -> s_load
#pragma unroll
        for (int o = 0; o < 16; ++o) {
            float u = Ur[o];
            a[o].x += t.x * u; a[o].y += t.y * u;
            a[o].z += t.z * u; a[o].w += t.w * u;
        }
    }
#pragma unroll
    for (int o = 0; o < 16; ++o)
        Out[(size_t)(og + o) * NQ + q] = a[o];
}

// ===================== fallback path (R5, known good) =====================

__global__ __launch_bounds__(256) void k1_chunk(
    const float* __restrict__ x, const float* __restrict__ Ucin,
    float* T, int r0, int nr)
{
    __shared__ float sU[11 * CIN];
    const int tid = threadIdx.x;
    for (int t = tid; t < nr * CIN; t += 256) {
        int lr = t >> 5, c = t & 31;
        sU[t] = Ucin[c * RK + (r0 + lr)];
    }
    __syncthreads();
    const int p = blockIdx.x * 256 + tid;
    float xv[CIN];
#pragma unroll
    for (int c = 0; c < CIN; ++c) xv[c] = x[c * NP + p];
#pragma unroll 1
    for (int lr = 0; lr < nr; ++lr) {
        float acc = 0.f;
#pragma unroll
        for (int c = 0; c < CIN; ++c) acc += xv[c] * sU[lr * CIN + c];
        T[(size_t)(SCR + lr) * NP + p] = acc;
    }
}

__global__ __launch_bounds__(256) void k2_chunk(
    const float* __restrict__ Ukh, const float* __restrict__ Ukw,
    const float* __restrict__ Ukd, float* T, int r0)
{
    __shared__ float sIn[5800];
    __shared__ float sA[5600];
    const int lr = blockIdx.z;
    const int r  = r0 + lr;
    const int h0 = blockIdx.x * 8, w0 = blockIdx.y * 8;
    const int tid = threadIdx.x;
    const float kh0 = Ukh[r], kh1 = Ukh[RK + r], kh2 = Ukh[2 * RK + r];
    const float kw0 = Ukw[r], kw1 = Ukw[RK + r], kw2 = Ukw[2 * RK + r];
    const float kd0 = Ukd[r], kd1 = Ukd[RK + r], kd2 = Ukd[2 * RK + r];
    const float* T1r = T + (size_t)(SCR + lr) * NP;

    for (int idx = tid; idx < 5800; idx += 256) {
        int d = idx % 58; int t2 = idx / 58; int ww = t2 % 10; int hh = t2 / 10;
        int gh = h0 + hh - 1, gw = w0 + ww - 1, gd = d - 1;
        float v = 0.f;
        if ((unsigned)gh < 56u && (unsigned)gw < 56u && (unsigned)gd < 56u)
            v = T1r[gh * HSTR + gw * 56 + gd];
        sIn[idx] = v;
    }
    __syncthreads();
    for (int idx = tid; idx < 5600; idx += 256) {
        int d = idx % 56; int t2 = idx / 56; int ww = t2 % 10; int hh = t2 / 10;
        const float* b = &sIn[(hh * 10 + ww) * 58 + d];
        sA[idx] = b[0] * kd0 + b[1] * kd1 + b[2] * kd2;
    }
    __syncthreads();
    const float k00 = kh0 * kw0, k01 = kh0 * kw1, k02 = kh0 * kw2;
    const float k10 = kh1 * kw0, k11 = kh1 * kw1, k12 = kh1 * kw2;
    const float k20 = kh2 * kw0, k21 = kh2 * kw1, k22 = kh2 * kw2;
    for (int idx = tid; idx < 3584; idx += 256) {
        int d = idx % 56; int t2 = idx / 56; int ww = t2 % 8; int hh = t2 / 8;
        const float* a = &sA[(hh * 10 + ww) * 56 + d];
        float acc = a[0]    * k00 + a[56]   * k01 + a[112]  * k02
                  + a[560]  * k10 + a[616]  * k11 + a[672]  * k12
                  + a[1120] * k20 + a[1176] * k21 + a[1232] * k22;
        T[(size_t)r * NP + (h0 + hh) * HSTR + (w0 + ww) * 56 + d] = acc;
    }
}

__global__ __launch_bounds__(256) void k3_out(
    float* T, const float* __restrict__ Ucout, const float* __restrict__ bias)
{
    __shared__ float sUo[RK * COUT];
    __shared__ float sB[COUT];
    const int tid = threadIdx.x;
    for (int t = tid; t < RK * COUT; t += 256) sUo[t] = Ucout[t];
    if (tid < COUT) sB[tid] = bias[tid];
    __syncthreads();
    const int p = blockIdx.x * 256 + tid;
    float acc[COUT];
#pragma unroll
    for (int o = 0; o < COUT; ++o) acc[o] = sB[o];
#pragma unroll 1
    for (int r = 0; r < RK; ++r) {
        float t = T[(size_t)r * NP + p];
        const float* Ur = &sUo[r * COUT];
#pragma unroll
        for (int o = 0; o < COUT; ++o) acc[o] += t * Ur[o];
    }
#pragma unroll
    for (int o = 0; o < COUT; ++o) T[(size_t)o * NP + p] = acc[o];
}

// ===================== launch =====================

extern "C" void kernel_launch(void* const* d_in, const int* in_sizes, int n_in,
                              void* d_out, int out_size, void* d_ws, size_t ws_size,
                              hipStream_t stream)
{
    const float* x     = (const float*)d_in[0];
    const float* Ukh   = (const float*)d_in[1];
    const float* Ukw   = (const float*)d_in[2];
    const float* Ukd   = (const float*)d_in[3];
    const float* Ucin  = (const float*)d_in[4];
    const float* Ucout = (const float*)d_in[5];
    const float* bias  = (const float*)d_in[6];

    const size_t t1_bytes = (size_t)RK * NP * sizeof(float);   // 37.2 MB

    if (ws_size >= t1_bytes + 8192) {
        float* T1 = (float*)d_ws;
        float* Ut = (float*)((char*)d_ws + t1_bytes);          // 6.8 KB
        k0_t<<<7, 256, 0, stream>>>(Ucin, Ut);
        k1n<<<NP / 256, 256, 0, stream>>>(x, Ut, T1);
        k2n<<<dim3(56, RK), 256, 0, stream>>>(T1, Ukw, Ukd);
        k3n<<<NQ / 64, 256, 0, stream>>>((const float4*)T1, Ucout, bias, Ukh,
                                         (float4*)d_out);
    } else {
        float* T = (float*)d_out;
        for (int r0 = 0; r0 < RK; r0 += 11) {
            int nr = (RK - r0 < 11) ? (RK - r0) : 11;
            k1_chunk<<<NP / 256, 256, 0, stream>>>(x, Ucin, T, r0, nr);
            k2_chunk<<<dim3(7, 7, nr), 256, 0, stream>>>(Ukh, Ukw, Ukd, T, r0);
        }
        k3_out<<<NP / 256, 256, 0, stream>>>(T, Ucout, bias);
    }
}